// Round 2
// baseline (359.627 us; speedup 1.0000x reference)
//
#include <hip/hip_runtime.h>
#include <hip/hip_bf16.h>
#include <stdint.h>

namespace {

constexpr int MTOT = 8192;   // 4 * 2048 rows of x
constexpr int NTOT = 4096;   // OUT_DIM
constexpr int KTOT = 4096;   // IN_DIM

constexpr int BM = 256, BN = 256, BK = 32;
constexpr int NT = KTOT / BK;     // 128 K-tiles

typedef __attribute__((ext_vector_type(8))) short bf16x8;
typedef __attribute__((ext_vector_type(4))) float f32x4;

__device__ inline unsigned short to_bf16(float f) {
    union { float f; uint32_t u; } v; v.f = f;
    return (unsigned short)((v.u + 0x7FFFu + ((v.u >> 16) & 1u)) >> 16);
}

// ---- Kernel 1: fp32 -> bf16 convert of x (8 elems / thread) ----
__global__ __launch_bounds__(256) void convert_x_kernel(const float* __restrict__ x,
                                                        unsigned short* __restrict__ xb) {
    int idx = blockIdx.x * 256 + threadIdx.x;
    const f32x4* xv = reinterpret_cast<const f32x4*>(x);
    f32x4 v0 = xv[2 * idx];
    f32x4 v1 = xv[2 * idx + 1];
    union { bf16x8 v; unsigned short s[8]; } o;
    o.s[0] = to_bf16(v0.x); o.s[1] = to_bf16(v0.y);
    o.s[2] = to_bf16(v0.z); o.s[3] = to_bf16(v0.w);
    o.s[4] = to_bf16(v1.x); o.s[5] = to_bf16(v1.y);
    o.s[6] = to_bf16(v1.z); o.s[7] = to_bf16(v1.w);
    reinterpret_cast<bf16x8*>(xb)[idx] = o.v;
}

// ---- Kernel 2: W[o][i] = sum_b a[b][o/512][i/512] * s[b][o%512][i%512], bf16 out ----
__global__ __launch_bounds__(256) void gen_w_kernel(const float* __restrict__ a,
                                                    const float* __restrict__ s,
                                                    unsigned short* __restrict__ w) {
    int idx = blockIdx.x * 256 + threadIdx.x;   // 4096 * 512 threads
    int o  = idx >> 9;
    int i8 = idx & 511;
    int i0 = i8 * 8;
    int obig = o >> 9, orow = o & 511;
    int ibig = i0 >> 9, icol = i0 & 511;

    float acc[8];
#pragma unroll
    for (int j = 0; j < 8; ++j) acc[j] = 0.f;

#pragma unroll
    for (int b = 0; b < 8; ++b) {
        float av = a[b * 64 + obig * 8 + ibig];
        const f32x4* sv = reinterpret_cast<const f32x4*>(s + b * 512 * 512 + orow * 512 + icol);
        f32x4 s0 = sv[0], s1 = sv[1];
        acc[0] += av * s0.x; acc[1] += av * s0.y; acc[2] += av * s0.z; acc[3] += av * s0.w;
        acc[4] += av * s1.x; acc[5] += av * s1.y; acc[6] += av * s1.z; acc[7] += av * s1.w;
    }
    union { bf16x8 v; unsigned short q[8]; } ov;
#pragma unroll
    for (int j = 0; j < 8; ++j) ov.q[j] = to_bf16(acc[j]);
    reinterpret_cast<bf16x8*>(w)[idx] = ov.v;
}

// ---- Kernel 3: C[m,n] = sum_k A[m,k] * B[n,k] ----
// 256x256 tile, BK=32, 8 waves (2M x 4N), 4-deep LDS ring, counted vmcnt pipeline.
// A: MTOT x KTOT bf16 row-major; B: NTOT x KTOT bf16 row-major; C: MTOT x NTOT f32
__global__ __launch_bounds__(512, 2)
void gemm_bt_kernel(const unsigned short* __restrict__ A,
                    const unsigned short* __restrict__ B,
                    float* __restrict__ C) {
    // 4 ring slots x (256x32 A + 256x32 B) bf16 = 128 KiB
    __shared__ __align__(16) unsigned short As[4][BM][BK];
    __shared__ __align__(16) unsigned short Bs[4][BN][BK];

    // XCD-aware bijective swizzle: 512 blocks, 8 XCDs, 64 blocks/XCD
    int bid = blockIdx.x;
    int swz = (bid & 7) * 64 + (bid >> 3);
    int bm = swz >> 4;                 // NTOT/BN = 16 tiles per row
    int bn = swz & 15;

    int tid  = threadIdx.x;
    int wid  = tid >> 6;               // 0..7
    int lane = tid & 63;
    int wm = wid >> 2, wn = wid & 3;   // wave owns 128x64 of C

    // ---- staging geometry (global source pre-swizzled, LDS dest linear) ----
    // row = 64 B = 4 lanes of 16 B; per issue a wave covers 16 rows.
    int srow  = lane >> 2;                              // 0..15
    int sslot = (lane & 3) ^ ((srow >> 1) & 3);         // XOR-swizzled 16B slot
    const unsigned short* ag0 = A + (size_t)(bm * BM + wid * 16 + srow) * KTOT + sslot * 8;
    const unsigned short* ag1 = ag0 + (size_t)128 * KTOT;
    const unsigned short* bg0 = B + (size_t)(bn * BN + wid * 16 + srow) * KTOT + sslot * 8;
    const unsigned short* bg1 = bg0 + (size_t)128 * KTOT;

    // ---- fragment-read geometry (swizzled read: slot = q ^ ((row>>1)&3)) ----
    int rl    = lane & 15;
    int rslot = (lane >> 4) ^ ((rl >> 1) & 3);          // lane-constant swizzled slot

    f32x4 acc[8][4];
#pragma unroll
    for (int m = 0; m < 8; ++m)
#pragma unroll
        for (int n = 0; n < 4; ++n) acc[m][n] = (f32x4)0.f;

    auto STAGE = [&](int s, int k0) {
        __builtin_amdgcn_global_load_lds(
            (const __attribute__((address_space(1))) void*)(ag0 + k0),
            (__attribute__((address_space(3))) void*)&As[s][wid * 16][0], 16, 0, 0);
        __builtin_amdgcn_global_load_lds(
            (const __attribute__((address_space(1))) void*)(ag1 + k0),
            (__attribute__((address_space(3))) void*)&As[s][128 + wid * 16][0], 16, 0, 0);
        __builtin_amdgcn_global_load_lds(
            (const __attribute__((address_space(1))) void*)(bg0 + k0),
            (__attribute__((address_space(3))) void*)&Bs[s][wid * 16][0], 16, 0, 0);
        __builtin_amdgcn_global_load_lds(
            (const __attribute__((address_space(1))) void*)(bg1 + k0),
            (__attribute__((address_space(3))) void*)&Bs[s][128 + wid * 16][0], 16, 0, 0);
    };

    auto BODY = [&](int s) {
        bf16x8 af[8], bf[4];
#pragma unroll
        for (int m = 0; m < 8; ++m)
            af[m] = *reinterpret_cast<const bf16x8*>(&As[s][wm * 128 + m * 16 + rl][rslot * 8]);
#pragma unroll
        for (int n = 0; n < 4; ++n)
            bf[n] = *reinterpret_cast<const bf16x8*>(&Bs[s][wn * 64 + n * 16 + rl][rslot * 8]);
        __builtin_amdgcn_s_setprio(1);
#pragma unroll
        for (int m = 0; m < 8; ++m)
#pragma unroll
            for (int n = 0; n < 4; ++n)
                acc[m][n] = __builtin_amdgcn_mfma_f32_16x16x32_bf16(af[m], bf[n], acc[m][n], 0, 0, 0);
        __builtin_amdgcn_s_setprio(0);
    };

    // ---- prologue: stage tiles 0,1,2; ensure tile 0 resident ----
    STAGE(0, 0);
    STAGE(1, BK);
    STAGE(2, 2 * BK);
    asm volatile("s_waitcnt vmcnt(8)" ::: "memory");
    __builtin_amdgcn_s_barrier();
    __builtin_amdgcn_sched_barrier(0);

    // ---- main loop: stage t+3 into slot last read at t-1; wait leaves 8 in flight ----
    for (int t = 0; t < NT - 3; ++t) {
        STAGE((t + 3) & 3, (t + 3) * BK);
        BODY(t & 3);
        asm volatile("s_waitcnt vmcnt(8)" ::: "memory");
        __builtin_amdgcn_s_barrier();
        __builtin_amdgcn_sched_barrier(0);
    }
    // ---- epilogue drain: 8 -> 4 -> 0 outstanding ----
    BODY((NT - 3) & 3);
    asm volatile("s_waitcnt vmcnt(4)" ::: "memory");
    __builtin_amdgcn_s_barrier();
    __builtin_amdgcn_sched_barrier(0);

    BODY((NT - 2) & 3);
    asm volatile("s_waitcnt vmcnt(0)" ::: "memory");
    __builtin_amdgcn_s_barrier();
    __builtin_amdgcn_sched_barrier(0);

    BODY((NT - 1) & 3);

    // ---- C write: per 16x16 frag, col = lane&15, row = (lane>>4)*4 + j ----
    int crow0 = bm * BM + wm * 128 + (lane >> 4) * 4;
    int ccol0 = bn * BN + wn * 64 + (lane & 15);
#pragma unroll
    for (int m = 0; m < 8; ++m)
#pragma unroll
        for (int n = 0; n < 4; ++n)
#pragma unroll
            for (int j = 0; j < 4; ++j) {
                size_t r = (size_t)(crow0 + m * 16 + j);
                size_t c = (size_t)(ccol0 + n * 16);
                C[r * NTOT + c] = acc[m][n][j];
            }
}

} // anonymous namespace

extern "C" void kernel_launch(void* const* d_in, const int* in_sizes, int n_in,
                              void* d_out, int out_size, void* d_ws, size_t ws_size,
                              hipStream_t stream) {
    const float* x = (const float*)d_in[0];   // (4,2048,4096) f32
    const float* a = (const float*)d_in[1];   // (8,8,8) f32
    const float* s = (const float*)d_in[2];   // (8,512,512) f32
    float* out = (float*)d_out;               // (4,2048,4096) f32

    unsigned short* xb = (unsigned short*)d_ws;                    // 64 MiB bf16 x
    unsigned short* wb = xb + (size_t)MTOT * KTOT;                 // 32 MiB bf16 W

    convert_x_kernel<<<(MTOT * KTOT / 8) / 256, 256, 0, stream>>>(x, xb);
    gen_w_kernel<<<(NTOT * KTOT / 8) / 256, 256, 0, stream>>>(a, s, wb);
    gemm_bt_kernel<<<(MTOT / 256) * (NTOT / 256), 512, 0, stream>>>(xb, wb, out);
}

// Round 3
// 296.245 us; speedup vs baseline: 1.2140x; 1.2140x over previous
//
#include <hip/hip_runtime.h>
#include <hip/hip_bf16.h>
#include <stdint.h>

namespace {

constexpr int MTOT = 8192;   // 4 * 2048 rows of x
constexpr int NTOT = 4096;   // OUT_DIM
constexpr int KTOT = 4096;   // IN_DIM

constexpr int BM = 256, BN = 256, BK = 32;
constexpr int NT = KTOT / BK;     // 128 K-tiles

typedef __attribute__((ext_vector_type(8))) short bf16x8;
typedef __attribute__((ext_vector_type(4))) float f32x4;

__device__ inline unsigned short to_bf16(float f) {
    union { float f; uint32_t u; } v; v.f = f;
    return (unsigned short)((v.u + 0x7FFFu + ((v.u >> 16) & 1u)) >> 16);
}

// ---- Kernel 1: fp32 -> bf16 convert of x (8 elems / thread) ----
__global__ __launch_bounds__(256) void convert_x_kernel(const float* __restrict__ x,
                                                        unsigned short* __restrict__ xb) {
    int idx = blockIdx.x * 256 + threadIdx.x;
    const f32x4* xv = reinterpret_cast<const f32x4*>(x);
    f32x4 v0 = xv[2 * idx];
    f32x4 v1 = xv[2 * idx + 1];
    union { bf16x8 v; unsigned short s[8]; } o;
    o.s[0] = to_bf16(v0.x); o.s[1] = to_bf16(v0.y);
    o.s[2] = to_bf16(v0.z); o.s[3] = to_bf16(v0.w);
    o.s[4] = to_bf16(v1.x); o.s[5] = to_bf16(v1.y);
    o.s[6] = to_bf16(v1.z); o.s[7] = to_bf16(v1.w);
    reinterpret_cast<bf16x8*>(xb)[idx] = o.v;
}

// ---- Kernel 2: W[o][i] = sum_b a[b][o/512][i/512] * s[b][o%512][i%512], bf16 out ----
__global__ __launch_bounds__(256) void gen_w_kernel(const float* __restrict__ a,
                                                    const float* __restrict__ s,
                                                    unsigned short* __restrict__ w) {
    int idx = blockIdx.x * 256 + threadIdx.x;   // 4096 * 512 threads
    int o  = idx >> 9;
    int i8 = idx & 511;
    int i0 = i8 * 8;
    int obig = o >> 9, orow = o & 511;
    int ibig = i0 >> 9, icol = i0 & 511;

    float acc[8];
#pragma unroll
    for (int j = 0; j < 8; ++j) acc[j] = 0.f;

#pragma unroll
    for (int b = 0; b < 8; ++b) {
        float av = a[b * 64 + obig * 8 + ibig];
        const f32x4* sv = reinterpret_cast<const f32x4*>(s + b * 512 * 512 + orow * 512 + icol);
        f32x4 s0 = sv[0], s1 = sv[1];
        acc[0] += av * s0.x; acc[1] += av * s0.y; acc[2] += av * s0.z; acc[3] += av * s0.w;
        acc[4] += av * s1.x; acc[5] += av * s1.y; acc[6] += av * s1.z; acc[7] += av * s1.w;
    }
    union { bf16x8 v; unsigned short q[8]; } ov;
#pragma unroll
    for (int j = 0; j < 8; ++j) ov.q[j] = to_bf16(acc[j]);
    reinterpret_cast<bf16x8*>(w)[idx] = ov.v;
}

// ---- Kernel 3: C[m,n] = sum_k A[m,k] * B[n,k] ----
// 256x256 tile, BK=32, 8 waves (2M x 4N), 4-deep LDS ring.
// 2 fine phases per K-tile, disjoint acc quadrants, counted vmcnt(8).
__global__ __launch_bounds__(512, 2)
void gemm_bt_kernel(const unsigned short* __restrict__ A,
                    const unsigned short* __restrict__ B,
                    float* __restrict__ C) {
    __shared__ __align__(16) unsigned short As[4][BM][BK];
    __shared__ __align__(16) unsigned short Bs[4][BN][BK];

    // XCD-aware bijective swizzle: 512 blocks, 8 XCDs, 64 blocks/XCD
    int bid = blockIdx.x;
    int swz = (bid & 7) * 64 + (bid >> 3);
    int bm = swz >> 4;                 // 16 bn-tiles per bm-row
    int bn = swz & 15;

    int tid  = threadIdx.x;
    int wid  = tid >> 6;               // 0..7
    int lane = tid & 63;
    int wm = wid >> 2, wn = wid & 3;   // wave owns 128x64 of C

    // staging geometry (pre-swizzled global source, linear LDS dest)
    int srow  = lane >> 2;                              // 0..15
    int sslot = (lane & 3) ^ ((srow >> 1) & 3);
    const unsigned short* ag0 = A + (size_t)(bm * BM + wid * 16 + srow) * KTOT + sslot * 8;
    const unsigned short* ag1 = ag0 + (size_t)128 * KTOT;
    const unsigned short* bg0 = B + (size_t)(bn * BN + wid * 16 + srow) * KTOT + sslot * 8;
    const unsigned short* bg1 = bg0 + (size_t)128 * KTOT;

    // fragment-read geometry (same XOR on read side)
    int rl    = lane & 15;
    int rslot = (lane >> 4) ^ ((rl >> 1) & 3);

    f32x4 acc[8][4];
#pragma unroll
    for (int m = 0; m < 8; ++m)
#pragma unroll
        for (int n = 0; n < 4; ++n) acc[m][n] = (f32x4)0.f;

    auto STAGE_A = [&](int s, int k0) {
        __builtin_amdgcn_global_load_lds(
            (const __attribute__((address_space(1))) void*)(ag0 + k0),
            (__attribute__((address_space(3))) void*)&As[s][wid * 16][0], 16, 0, 0);
        __builtin_amdgcn_global_load_lds(
            (const __attribute__((address_space(1))) void*)(ag1 + k0),
            (__attribute__((address_space(3))) void*)&As[s][128 + wid * 16][0], 16, 0, 0);
    };
    auto STAGE_B = [&](int s, int k0) {
        __builtin_amdgcn_global_load_lds(
            (const __attribute__((address_space(1))) void*)(bg0 + k0),
            (__attribute__((address_space(3))) void*)&Bs[s][wid * 16][0], 16, 0, 0);
        __builtin_amdgcn_global_load_lds(
            (const __attribute__((address_space(1))) void*)(bg1 + k0),
            (__attribute__((address_space(3))) void*)&Bs[s][128 + wid * 16][0], 16, 0, 0);
    };

    bf16x8 bfr[4];   // B frags live across both phases of an iteration

    // phase 0: read A m0-3 + all B, stage next A, MFMA quadrant m0-3
    auto PH0 = [&](int s, bool st, int ss, int k0) {
        bf16x8 afr[4];
#pragma unroll
        for (int m = 0; m < 4; ++m)
            afr[m] = *reinterpret_cast<const bf16x8*>(&As[s][wm * 128 + m * 16 + rl][rslot * 8]);
#pragma unroll
        for (int n = 0; n < 4; ++n)
            bfr[n] = *reinterpret_cast<const bf16x8*>(&Bs[s][wn * 64 + n * 16 + rl][rslot * 8]);
        if (st) STAGE_A(ss, k0);
        __builtin_amdgcn_s_barrier();
        asm volatile("s_waitcnt lgkmcnt(0)" ::: "memory");
        __builtin_amdgcn_sched_barrier(0);
        __builtin_amdgcn_s_setprio(1);
#pragma unroll
        for (int m = 0; m < 4; ++m)
#pragma unroll
            for (int n = 0; n < 4; ++n)
                acc[m][n] = __builtin_amdgcn_mfma_f32_16x16x32_bf16(afr[m], bfr[n], acc[m][n], 0, 0, 0);
        __builtin_amdgcn_s_setprio(0);
        __builtin_amdgcn_s_barrier();
    };
    // phase 1: read A m4-7 (B reused), stage next B, MFMA quadrant m4-7.
    // trailing vmcnt/barrier handled by caller.
    auto PH1 = [&](int s, bool st, int ss, int k0) {
        bf16x8 afr[4];
#pragma unroll
        for (int m = 0; m < 4; ++m)
            afr[m] = *reinterpret_cast<const bf16x8*>(&As[s][wm * 128 + (m + 4) * 16 + rl][rslot * 8]);
        if (st) STAGE_B(ss, k0);
        __builtin_amdgcn_s_barrier();
        asm volatile("s_waitcnt lgkmcnt(0)" ::: "memory");
        __builtin_amdgcn_sched_barrier(0);
        __builtin_amdgcn_s_setprio(1);
#pragma unroll
        for (int m = 0; m < 4; ++m)
#pragma unroll
            for (int n = 0; n < 4; ++n)
                acc[m + 4][n] = __builtin_amdgcn_mfma_f32_16x16x32_bf16(afr[m], bfr[n], acc[m + 4][n], 0, 0, 0);
        __builtin_amdgcn_s_setprio(0);
    };

    // ---- prologue: stage tiles 0,1,2; ensure tile 0 resident (12 issued, 8 left) ----
    STAGE_A(0, 0);          STAGE_B(0, 0);
    STAGE_A(1, BK);         STAGE_B(1, BK);
    STAGE_A(2, 2 * BK);     STAGE_B(2, 2 * BK);
    asm volatile("s_waitcnt vmcnt(8)" ::: "memory");
    __builtin_amdgcn_s_barrier();

    // ---- main loop: 124 staged iterations, ring slots compile-time via x4 unroll ----
    for (int tb = 0; tb < NT - 4; tb += 4) {
#pragma unroll
        for (int u = 0; u < 4; ++u) {
            int s = u, ss = (u + 3) & 3;
            int k0 = (tb + u + 3) * BK;
            PH0(s, true, ss, k0);
            PH1(s, true, ss, k0);
            asm volatile("s_waitcnt vmcnt(8)" ::: "memory");
            __builtin_amdgcn_s_barrier();
        }
    }
    // t = NT-4 = 124: last staged iteration (stages tile 127 into slot 3)
    PH0(0, true, 3, (NT - 1) * BK);
    PH1(0, true, 3, (NT - 1) * BK);
    asm volatile("s_waitcnt vmcnt(8)" ::: "memory");
    __builtin_amdgcn_s_barrier();
    // t = 125..127: drain 8 -> 4 -> 0
    PH0(1, false, 0, 0);
    PH1(1, false, 0, 0);
    asm volatile("s_waitcnt vmcnt(4)" ::: "memory");
    __builtin_amdgcn_s_barrier();
    PH0(2, false, 0, 0);
    PH1(2, false, 0, 0);
    asm volatile("s_waitcnt vmcnt(0)" ::: "memory");
    __builtin_amdgcn_s_barrier();
    PH0(3, false, 0, 0);
    PH1(3, false, 0, 0);

    // ---- C write: per 16x16 frag, col = lane&15, row = (lane>>4)*4 + j ----
    int crow0 = bm * BM + wm * 128 + (lane >> 4) * 4;
    int ccol0 = bn * BN + wn * 64 + (lane & 15);
#pragma unroll
    for (int m = 0; m < 8; ++m)
#pragma unroll
        for (int n = 0; n < 4; ++n)
#pragma unroll
            for (int j = 0; j < 4; ++j) {
                size_t r = (size_t)(crow0 + m * 16 + j);
                size_t c = (size_t)(ccol0 + n * 16);
                C[r * NTOT + c] = acc[m][n][j];
            }
}

} // anonymous namespace

extern "C" void kernel_launch(void* const* d_in, const int* in_sizes, int n_in,
                              void* d_out, int out_size, void* d_ws, size_t ws_size,
                              hipStream_t stream) {
    const float* x = (const float*)d_in[0];   // (4,2048,4096) f32
    const float* a = (const float*)d_in[1];   // (8,8,8) f32
    const float* s = (const float*)d_in[2];   // (8,512,512) f32
    float* out = (float*)d_out;               // (4,2048,4096) f32

    unsigned short* xb = (unsigned short*)d_ws;                    // 64 MiB bf16 x
    unsigned short* wb = xb + (size_t)MTOT * KTOT;                 // 32 MiB bf16 W

    convert_x_kernel<<<(MTOT * KTOT / 8) / 256, 256, 0, stream>>>(x, xb);
    gen_w_kernel<<<(NTOT * KTOT / 8) / 256, 256, 0, stream>>>(a, s, wb);
    gemm_bt_kernel<<<(MTOT / 256) * (NTOT / 256), 512, 0, stream>>>(xb, wb, out);
}